// Round 3
// baseline (4220.553 us; speedup 1.0000x reference)
//
#include <hip/hip_runtime.h>

#define DD 128
#define NMESH 30000
#define NOBJ 2000
#define EMMN 240000
#define EMON 60000

typedef unsigned short u16;
typedef short short8 __attribute__((ext_vector_type(8)));
typedef short short4v __attribute__((ext_vector_type(4)));
typedef float f32x4 __attribute__((ext_vector_type(4)));
typedef __bf16 bf16x8 __attribute__((ext_vector_type(8)));

union FragCvt { short8 s; bf16x8 b; };

static __device__ __forceinline__ u16 f2bf(float f) {
  union { float f; unsigned u; } v; v.f = f;
  unsigned r = v.u + 0x7FFFu + ((v.u >> 16) & 1u);
  return (u16)(r >> 16);
}
static __device__ __forceinline__ float bf2f(u16 u) {
  union { unsigned u; float f; } v; v.u = ((unsigned)u) << 16; return v.f;
}
// swizzle: XOR byte-bits 4..6 with row&7 -> conflict-free ds_read_b128 column slices (T2)
static __device__ __forceinline__ int swz256(int row, int b) {
  return row * 256 + (b ^ ((row & 7) << 4));
}
static __device__ __forceinline__ bf16x8 ldsFrag(const u16* s, int row, int kByte) {
  FragCvt u; u.s = *(const short8*)((const char*)s + swz256(row, kByte));
  return u.b;
}

// stage one 128x128 bf16 weight block (from transposed [128][rowLen] global) into swizzled LDS
static __device__ __forceinline__ void stage_w(u16* sW, const u16* src, int rowLen, int colOff, int tid) {
  const int wrow = tid >> 1, wh = tid & 1;
  const u16* w = src + (size_t)wrow * rowLen + colOff + wh * 64;
  #pragma unroll
  for (int j = 0; j < 8; ++j) {
    short8 v = *(const short8*)(w + j * 8);
    *(short8*)((char*)sW + swz256(wrow, wh * 128 + j * 16)) = v;
  }
}

// one K=128 GEMM part: acc[2][4] covers 32 rows x 64 cols per wave
static __device__ __forceinline__ void mfma_128k(const u16* sIn, const u16* sW,
                                                 int wr, int wc, int lrow, int lk,
                                                 f32x4 acc[2][4]) {
  #pragma unroll
  for (int kc = 0; kc < 4; ++kc) {
    bf16x8 a0 = ldsFrag(sIn, wr * 32 + lrow, kc * 64 + lk * 16);
    bf16x8 a1 = ldsFrag(sIn, wr * 32 + 16 + lrow, kc * 64 + lk * 16);
    #pragma unroll
    for (int ct = 0; ct < 4; ++ct) {
      bf16x8 b = ldsFrag(sW, wc * 64 + ct * 16 + lrow, kc * 64 + lk * 16);
      acc[0][ct] = __builtin_amdgcn_mfma_f32_16x16x32_bf16(a0, b, acc[0][ct], 0, 0, 0);
      acc[1][ct] = __builtin_amdgcn_mfma_f32_16x16x32_bf16(a1, b, acc[1][ct], 0, 0, 0);
    }
  }
}

// bias+relu, write bf16 back to sIn as next layer's A, zero acc
static __device__ __forceinline__ void transition_relu(u16* sIn, const float* sBias, int biasOff,
                                                       int wr, int wc, int lrow, int lk,
                                                       f32x4 acc[2][4]) {
  #pragma unroll
  for (int rt = 0; rt < 2; ++rt) {
    #pragma unroll
    for (int ct = 0; ct < 4; ++ct) {
      const int col = wc * 64 + ct * 16 + lrow;
      const float bias = sBias[biasOff + col];
      #pragma unroll
      for (int r = 0; r < 4; ++r) {
        const int orow = wr * 32 + rt * 16 + lk * 4 + r;
        float v = acc[rt][ct][r] + bias;
        v = fmaxf(v, 0.f);
        *(u16*)((char*)sIn + swz256(orow, col * 2)) = f2bf(v);
        acc[rt][ct][r] = 0.f;
      }
    }
  }
}

static __device__ __forceinline__ void store_h3(float* sH, const float* sBias,
                                                int wr, int wc, int lrow, int lk,
                                                f32x4 acc[2][4]) {
  #pragma unroll
  for (int rt = 0; rt < 2; ++rt) {
    #pragma unroll
    for (int ct = 0; ct < 4; ++ct) {
      const int col = wc * 64 + ct * 16 + lrow;
      const float bias = sBias[256 + col];
      #pragma unroll
      for (int r = 0; r < 4; ++r) {
        const int orow = wr * 32 + rt * 16 + lk * 4 + r;
        sH[orow * 132 + col] = acc[rt][ct][r] + bias;
      }
    }
  }
}

// ---------------- edge conv: msg = LN(MLP([x_dst[i], x_src[j], ea])); ea += msg; agg[dst] += msg
__global__ __launch_bounds__(256, 2) void edge_conv_kernel(
    const u16* __restrict__ xsrc, const u16* __restrict__ xdst,
    const int* __restrict__ ei, const int E,
    const float* __restrict__ ea_f32, u16* __restrict__ ea_bf,
    const u16* __restrict__ W0T, const u16* __restrict__ W1T, const u16* __restrict__ W2T,
    const float* __restrict__ b0, const float* __restrict__ b1, const float* __restrict__ b2,
    const float* __restrict__ gg, const float* __restrict__ btp,
    float* __restrict__ agg)
{
  __shared__ u16 sIn[64 * 128];
  __shared__ __align__(16) char sWHraw[64 * 132 * 4];  // sW (32KB bf16) and sH (f32, pad 132) union
  __shared__ float sBias[5 * 128];
  __shared__ int sIdx[128];
  u16* sW = (u16*)sWHraw;
  float* sH = (float*)sWHraw;

  const int tid = threadIdx.x;
  const int wave = tid >> 6, lane = tid & 63;
  const int lrow = lane & 15, lk = lane >> 4;
  const int wr = wave >> 1, wc = wave & 1;
  const int e0 = blockIdx.x * 64;
  const int row = tid >> 2, seg = tid & 3;

  if (tid < 128) {
    sBias[tid] = b0[tid];
    sBias[128 + tid] = b1[tid];
    sBias[256 + tid] = b2[tid];
    sBias[384 + tid] = gg[tid];
    sBias[512 + tid] = btp[tid];
  }
  if (tid < 64) {
    int e = e0 + tid; if (e >= E) e = E - 1;
    sIdx[tid] = ei[e];          // src
    sIdx[64 + tid] = ei[E + e]; // dst
  }
  __syncthreads();

  const int eRow = (e0 + row < E) ? (e0 + row) : (E - 1);
  const f32x4 zero = {0.f, 0.f, 0.f, 0.f};
  f32x4 acc[2][4];
  #pragma unroll
  for (int i = 0; i < 2; ++i)
    #pragma unroll
    for (int j = 0; j < 4; ++j) acc[i][j] = zero;

  // ----- layer 1: three K=128 parts (x_dst, x_src, ea) -----
  #pragma unroll
  for (int p = 0; p < 3; ++p) {
    if (p < 2) {
      const u16* xb = (p == 0) ? xdst : xsrc;
      const int idx = (p == 0) ? sIdx[64 + row] : sIdx[row];
      const u16* srow = xb + (size_t)idx * DD;
      #pragma unroll
      for (int j = 0; j < 4; ++j) {
        short8 v = *(const short8*)(srow + seg * 32 + j * 8);
        *(short8*)((char*)sIn + swz256(row, seg * 64 + j * 16)) = v;
      }
    } else if (ea_f32) {
      const float* er = ea_f32 + (size_t)eRow * DD;
      #pragma unroll
      for (int j = 0; j < 4; ++j) {
        const int c0 = seg * 32 + j * 8;
        f32x4 f0 = *(const f32x4*)(er + c0);
        f32x4 f1 = *(const f32x4*)(er + c0 + 4);
        short8 v;
        #pragma unroll
        for (int q = 0; q < 4; ++q) { v[q] = (short)f2bf(f0[q]); v[4 + q] = (short)f2bf(f1[q]); }
        *(short8*)((char*)sIn + swz256(row, seg * 64 + j * 16)) = v;
      }
    } else {
      const u16* er = ea_bf + (size_t)eRow * DD;
      #pragma unroll
      for (int j = 0; j < 4; ++j) {
        short8 v = *(const short8*)(er + seg * 32 + j * 8);
        *(short8*)((char*)sIn + swz256(row, seg * 64 + j * 16)) = v;
      }
    }
    stage_w(sW, W0T, 384, p * 128, tid);
    __syncthreads();
    mfma_128k(sIn, sW, wr, wc, lrow, lk, acc);
    __syncthreads();
  }

  transition_relu(sIn, sBias, 0, wr, wc, lrow, lk, acc);
  stage_w(sW, W1T, 128, 0, tid);
  __syncthreads();
  mfma_128k(sIn, sW, wr, wc, lrow, lk, acc);
  __syncthreads();

  transition_relu(sIn, sBias, 128, wr, wc, lrow, lk, acc);
  stage_w(sW, W2T, 128, 0, tid);
  __syncthreads();
  mfma_128k(sIn, sW, wr, wc, lrow, lk, acc);
  __syncthreads();                 // all L3 B-reads done before sH overwrites sW

  store_h3(sH, sBias, wr, wc, lrow, lk, acc);
  __syncthreads();

  // ----- epilogue: LN per edge row, residual into ea (bf16), atomic aggregate -----
  {
    const float* hrow = sH + row * 132 + seg * 32;
    f32x4 vv[8];
    float s1 = 0.f, s2 = 0.f;
    #pragma unroll
    for (int j = 0; j < 8; ++j) {
      vv[j] = *(const f32x4*)(hrow + j * 4);
      #pragma unroll
      for (int q = 0; q < 4; ++q) { s1 += vv[j][q]; s2 += vv[j][q] * vv[j][q]; }
    }
    s1 += __shfl_xor(s1, 1); s1 += __shfl_xor(s1, 2);
    s2 += __shfl_xor(s2, 1); s2 += __shfl_xor(s2, 2);
    const float m = s1 * (1.f / 128.f);
    const float var = s2 * (1.f / 128.f) - m * m;
    const float rstd = rsqrtf(var + 1e-5f);
    const int e = e0 + row;
    if (e < E) {
      const int dst = sIdx[64 + row];
      float* aggRow = agg + (size_t)dst * DD;
      u16* eaRow = ea_bf + (size_t)e * DD + seg * 32;
      float eold[32];
      if (ea_f32) {
        const float* er = ea_f32 + (size_t)e * DD + seg * 32;
        #pragma unroll
        for (int j = 0; j < 8; ++j) {
          f32x4 t = *(const f32x4*)(er + j * 4);
          #pragma unroll
          for (int q = 0; q < 4; ++q) eold[j * 4 + q] = t[q];
        }
      } else {
        #pragma unroll
        for (int j4 = 0; j4 < 4; ++j4) {
          short8 t = *(const short8*)(eaRow + j4 * 8);
          #pragma unroll
          for (int q = 0; q < 8; ++q) eold[j4 * 8 + q] = bf2f((u16)t[q]);
        }
      }
      #pragma unroll
      for (int j4 = 0; j4 < 4; ++j4) {
        short8 en;
        #pragma unroll
        for (int q = 0; q < 8; ++q) {
          const int cl = j4 * 8 + q;
          const int c = seg * 32 + cl;
          const float msg = (vv[cl >> 2][cl & 3] - m) * rstd * sBias[384 + c] + sBias[512 + c];
          en[q] = (short)f2bf(eold[cl] + msg);
          unsafeAtomicAdd(aggRow + c, msg);
        }
        *(short8*)(eaRow + j4 * 8) = en;
      }
    }
  }
}

// ---------------- node conv: x += LN(MLP([x, aggr]))
__global__ __launch_bounds__(256, 2) void node_conv_kernel(
    u16* __restrict__ x_bf, const float* __restrict__ aggin,
    float* __restrict__ x_f32, const int N,
    const u16* __restrict__ W0T, const u16* __restrict__ W1T, const u16* __restrict__ W2T,
    const float* __restrict__ b0, const float* __restrict__ b1, const float* __restrict__ b2,
    const float* __restrict__ gg, const float* __restrict__ btp)
{
  __shared__ u16 sIn[64 * 128];
  __shared__ __align__(16) char sWHraw[64 * 132 * 4];
  __shared__ float sBias[5 * 128];
  u16* sW = (u16*)sWHraw;
  float* sH = (float*)sWHraw;

  const int tid = threadIdx.x;
  const int wave = tid >> 6, lane = tid & 63;
  const int lrow = lane & 15, lk = lane >> 4;
  const int wr = wave >> 1, wc = wave & 1;
  const int n0 = blockIdx.x * 64;
  const int row = tid >> 2, seg = tid & 3;
  const int nRow = (n0 + row < N) ? (n0 + row) : (N - 1);

  if (tid < 128) {
    sBias[tid] = b0[tid];
    sBias[128 + tid] = b1[tid];
    sBias[256 + tid] = b2[tid];
    sBias[384 + tid] = gg[tid];
    sBias[512 + tid] = btp[tid];
  }
  __syncthreads();

  const f32x4 zero = {0.f, 0.f, 0.f, 0.f};
  f32x4 acc[2][4];
  #pragma unroll
  for (int i = 0; i < 2; ++i)
    #pragma unroll
    for (int j = 0; j < 4; ++j) acc[i][j] = zero;

  // part 0: x
  {
    const u16* srow = x_bf + (size_t)nRow * DD;
    #pragma unroll
    for (int j = 0; j < 4; ++j) {
      short8 v = *(const short8*)(srow + seg * 32 + j * 8);
      *(short8*)((char*)sIn + swz256(row, seg * 64 + j * 16)) = v;
    }
    stage_w(sW, W0T, 256, 0, tid);
  }
  __syncthreads();
  mfma_128k(sIn, sW, wr, wc, lrow, lk, acc);
  __syncthreads();
  // part 1: aggr (f32 -> bf16)
  {
    const float* ar = aggin + (size_t)nRow * DD;
    #pragma unroll
    for (int j = 0; j < 4; ++j) {
      const int c0 = seg * 32 + j * 8;
      f32x4 f0 = *(const f32x4*)(ar + c0);
      f32x4 f1 = *(const f32x4*)(ar + c0 + 4);
      short8 v;
      #pragma unroll
      for (int q = 0; q < 4; ++q) { v[q] = (short)f2bf(f0[q]); v[4 + q] = (short)f2bf(f1[q]); }
      *(short8*)((char*)sIn + swz256(row, seg * 64 + j * 16)) = v;
    }
    stage_w(sW, W0T, 256, 128, tid);
  }
  __syncthreads();
  mfma_128k(sIn, sW, wr, wc, lrow, lk, acc);
  __syncthreads();

  transition_relu(sIn, sBias, 0, wr, wc, lrow, lk, acc);
  stage_w(sW, W1T, 128, 0, tid);
  __syncthreads();
  mfma_128k(sIn, sW, wr, wc, lrow, lk, acc);
  __syncthreads();

  transition_relu(sIn, sBias, 128, wr, wc, lrow, lk, acc);
  stage_w(sW, W2T, 128, 0, tid);
  __syncthreads();
  mfma_128k(sIn, sW, wr, wc, lrow, lk, acc);
  __syncthreads();

  store_h3(sH, sBias, wr, wc, lrow, lk, acc);
  __syncthreads();

  // epilogue: LN + residual, write f32 (d_out) and bf16 copy
  {
    const float* hrow = sH + row * 132 + seg * 32;
    f32x4 vv[8];
    float s1 = 0.f, s2 = 0.f;
    #pragma unroll
    for (int j = 0; j < 8; ++j) {
      vv[j] = *(const f32x4*)(hrow + j * 4);
      #pragma unroll
      for (int q = 0; q < 4; ++q) { s1 += vv[j][q]; s2 += vv[j][q] * vv[j][q]; }
    }
    s1 += __shfl_xor(s1, 1); s1 += __shfl_xor(s1, 2);
    s2 += __shfl_xor(s2, 1); s2 += __shfl_xor(s2, 2);
    const float m = s1 * (1.f / 128.f);
    const float var = s2 * (1.f / 128.f) - m * m;
    const float rstd = rsqrtf(var + 1e-5f);
    const int n = n0 + row;
    if (n < N) {
      float* xr = x_f32 + (size_t)n * DD + seg * 32;
      u16* xb = x_bf + (size_t)n * DD + seg * 32;
      #pragma unroll
      for (int j = 0; j < 8; ++j) {
        f32x4 xold = *(const f32x4*)(xr + j * 4);
        f32x4 nv;
        short4v pb;
        #pragma unroll
        for (int q = 0; q < 4; ++q) {
          const int c = seg * 32 + j * 4 + q;
          const float ln = (vv[j][q] - m) * rstd * sBias[384 + c] + sBias[512 + c];
          nv[q] = xold[q] + ln;
          pb[q] = (short)f2bf(nv[q]);
        }
        *(f32x4*)(xr + j * 4) = nv;
        *(short4v*)(xb + j * 4) = pb;
      }
    }
  }
}

// ---------------- prep: weights f32 [4][K][128] -> bf16 transposed [4][128][K]
__global__ void prep_w_kernel(const float* __restrict__ src, u16* __restrict__ dst, int K) {
  int i = blockIdx.x * blockDim.x + threadIdx.x;
  int total = 4 * K * 128;
  if (i < total) {
    int n = i & 127;
    int k = (i >> 7) % K;
    int sl = i / (K * 128);
    dst[((size_t)sl * 128 + n) * K + k] = f2bf(src[i]);
  }
}

// prep: x f32 -> d_out working copy + bf16 copies
__global__ void prep_x_kernel(const float* __restrict__ xm, const float* __restrict__ xo,
                              float* __restrict__ xf, u16* __restrict__ xmb, u16* __restrict__ xob) {
  int i = blockIdx.x * blockDim.x + threadIdx.x;
  const int tm = NMESH * DD;
  const int to = NOBJ * DD;
  if (i < tm) { float v = xm[i]; xf[i] = v; xmb[i] = f2bf(v); }
  else if (i < tm + to) { int j = i - tm; float v = xo[j]; xf[tm + j] = v; xob[j] = f2bf(v); }
}

extern "C" void kernel_launch(void* const* d_in, const int* in_sizes, int n_in,
                              void* d_out, int out_size, void* d_ws, size_t ws_size,
                              hipStream_t stream)
{
  const float* x_mesh = (const float*)d_in[0];
  const float* x_obj  = (const float*)d_in[1];
  const int*   ei_mm  = (const int*)d_in[2];
  const int*   ei_mo  = (const int*)d_in[3];
  const float* ea_mm  = (const float*)d_in[4];
  const float* ea_mo  = (const float*)d_in[5];
  const float* eW0 = (const float*)d_in[6];
  const float* eb0 = (const float*)d_in[7];
  const float* eW1 = (const float*)d_in[8];
  const float* eb1 = (const float*)d_in[9];
  const float* eW2 = (const float*)d_in[10];
  const float* eb2 = (const float*)d_in[11];
  const float* eg  = (const float*)d_in[12];
  const float* ebt = (const float*)d_in[13];
  const float* nW0 = (const float*)d_in[14];
  const float* nb0 = (const float*)d_in[15];
  const float* nW1 = (const float*)d_in[16];
  const float* nb1 = (const float*)d_in[17];
  const float* nW2 = (const float*)d_in[18];
  const float* nb2 = (const float*)d_in[19];
  const float* ng  = (const float*)d_in[20];
  const float* nbt = (const float*)d_in[21];

  u16* eamm_bf = (u16*)d_ws;
  u16* eamo_bf = eamm_bf + (size_t)EMMN * DD;
  u16* xm_bf   = eamo_bf + (size_t)EMON * DD;
  u16* xo_bf   = xm_bf + (size_t)NMESH * DD;
  float* agg_m = (float*)(xo_bf + (size_t)NOBJ * DD);
  float* agg_o = agg_m + (size_t)NMESH * DD;
  u16* eW0T = (u16*)(agg_o + (size_t)NOBJ * DD);
  u16* eW1T = eW0T + (size_t)4 * 128 * 384;
  u16* eW2T = eW1T + (size_t)4 * 128 * 128;
  u16* nW0T = eW2T + (size_t)4 * 128 * 128;
  u16* nW1T = nW0T + (size_t)4 * 128 * 256;
  u16* nW2T = nW1T + (size_t)4 * 128 * 128;

  float* xf_m = (float*)d_out;
  float* xf_o = xf_m + (size_t)NMESH * DD;

  prep_w_kernel<<<768, 256, 0, stream>>>(eW0, eW0T, 384);
  prep_w_kernel<<<256, 256, 0, stream>>>(eW1, eW1T, 128);
  prep_w_kernel<<<256, 256, 0, stream>>>(eW2, eW2T, 128);
  prep_w_kernel<<<512, 256, 0, stream>>>(nW0, nW0T, 256);
  prep_w_kernel<<<256, 256, 0, stream>>>(nW1, nW1T, 128);
  prep_w_kernel<<<256, 256, 0, stream>>>(nW2, nW2T, 128);
  prep_x_kernel<<<16000, 256, 0, stream>>>(x_mesh, x_obj, xf_m, xm_bf, xo_bf);

  for (int s = 0; s < 2; ++s) {
    hipMemsetAsync(agg_m, 0, (size_t)NMESH * DD * sizeof(float), stream);
    hipMemsetAsync(agg_o, 0, (size_t)NOBJ * DD * sizeof(float), stream);
    {
      int sl = 0 * 2 + s;
      edge_conv_kernel<<<EMMN / 64, 256, 0, stream>>>(
          xm_bf, xm_bf, ei_mm, EMMN,
          (s == 0) ? ea_mm : (const float*)nullptr, eamm_bf,
          eW0T + (size_t)sl * 128 * 384, eW1T + (size_t)sl * 128 * 128, eW2T + (size_t)sl * 128 * 128,
          eb0 + sl * 128, eb1 + sl * 128, eb2 + sl * 128, eg + sl * 128, ebt + sl * 128,
          agg_m);
    }
    {
      int sl = 1 * 2 + s;
      edge_conv_kernel<<<(EMON + 63) / 64, 256, 0, stream>>>(
          xm_bf, xo_bf, ei_mo, EMON,
          (s == 0) ? ea_mo : (const float*)nullptr, eamo_bf,
          eW0T + (size_t)sl * 128 * 384, eW1T + (size_t)sl * 128 * 128, eW2T + (size_t)sl * 128 * 128,
          eb0 + sl * 128, eb1 + sl * 128, eb2 + sl * 128, eg + sl * 128, ebt + sl * 128,
          agg_o);
    }
    {
      int sl = 0 * 2 + s;
      node_conv_kernel<<<(NMESH + 63) / 64, 256, 0, stream>>>(
          xm_bf, agg_m, xf_m, NMESH,
          nW0T + (size_t)sl * 128 * 256, nW1T + (size_t)sl * 128 * 128, nW2T + (size_t)sl * 128 * 128,
          nb0 + sl * 128, nb1 + sl * 128, nb2 + sl * 128, ng + sl * 128, nbt + sl * 128);
    }
    {
      int sl = 1 * 2 + s;
      node_conv_kernel<<<(NOBJ + 63) / 64, 256, 0, stream>>>(
          xo_bf, agg_o, xf_o, NOBJ,
          nW0T + (size_t)sl * 128 * 256, nW1T + (size_t)sl * 128 * 128, nW2T + (size_t)sl * 128 * 128,
          nb0 + sl * 128, nb1 + sl * 128, nb2 + sl * 128, ng + sl * 128, nbt + sl * 128);
    }
  }
}

// Round 4
// 683.478 us; speedup vs baseline: 6.1751x; 6.1751x over previous
//
#include <hip/hip_runtime.h>

#define DD 128
#define NMESH 30000
#define NOBJ 2000
#define EMMN 240000
#define EMON 60000

typedef unsigned short u16;
typedef short short8 __attribute__((ext_vector_type(8)));
typedef short short4v __attribute__((ext_vector_type(4)));
typedef float f32x4 __attribute__((ext_vector_type(4)));
typedef __bf16 bf16x8 __attribute__((ext_vector_type(8)));

union FragCvt { short8 s; bf16x8 b; };

static __device__ __forceinline__ u16 f2bf(float f) {
  union { float f; unsigned u; } v; v.f = f;
  unsigned r = v.u + 0x7FFFu + ((v.u >> 16) & 1u);
  return (u16)(r >> 16);
}
static __device__ __forceinline__ float bf2f(u16 u) {
  union { unsigned u; float f; } v; v.u = ((unsigned)u) << 16; return v.f;
}
// swizzle: XOR byte-bits 4..6 with row&7 -> conflict-free ds_read_b128 column slices (T2)
static __device__ __forceinline__ int swz256(int row, int b) {
  return row * 256 + (b ^ ((row & 7) << 4));
}
static __device__ __forceinline__ bf16x8 ldsFrag(const u16* s, int row, int kByte) {
  FragCvt u; u.s = *(const short8*)((const char*)s + swz256(row, kByte));
  return u.b;
}

// stage one 128x128 bf16 weight block (from transposed [128][rowLen] global) into swizzled LDS
static __device__ __forceinline__ void stage_w(u16* sW, const u16* src, int rowLen, int colOff, int tid) {
  const int wrow = tid >> 1, wh = tid & 1;
  const u16* w = src + (size_t)wrow * rowLen + colOff + wh * 64;
  #pragma unroll
  for (int j = 0; j < 8; ++j) {
    short8 v = *(const short8*)(w + j * 8);
    *(short8*)((char*)sW + swz256(wrow, wh * 128 + j * 16)) = v;
  }
}

// one K=128 GEMM part: acc[2][4] covers 32 rows x 64 cols per wave
static __device__ __forceinline__ void mfma_128k(const u16* sIn, const u16* sW,
                                                 int wr, int wc, int lrow, int lk,
                                                 f32x4 acc[2][4]) {
  #pragma unroll
  for (int kc = 0; kc < 4; ++kc) {
    bf16x8 a0 = ldsFrag(sIn, wr * 32 + lrow, kc * 64 + lk * 16);
    bf16x8 a1 = ldsFrag(sIn, wr * 32 + 16 + lrow, kc * 64 + lk * 16);
    #pragma unroll
    for (int ct = 0; ct < 4; ++ct) {
      bf16x8 b = ldsFrag(sW, wc * 64 + ct * 16 + lrow, kc * 64 + lk * 16);
      acc[0][ct] = __builtin_amdgcn_mfma_f32_16x16x32_bf16(a0, b, acc[0][ct], 0, 0, 0);
      acc[1][ct] = __builtin_amdgcn_mfma_f32_16x16x32_bf16(a1, b, acc[1][ct], 0, 0, 0);
    }
  }
}

// bias+relu, write bf16 back to sIn as next layer's A, zero acc
static __device__ __forceinline__ void transition_relu(u16* sIn, const float* sBias, int biasOff,
                                                       int wr, int wc, int lrow, int lk,
                                                       f32x4 acc[2][4]) {
  #pragma unroll
  for (int rt = 0; rt < 2; ++rt) {
    #pragma unroll
    for (int ct = 0; ct < 4; ++ct) {
      const int col = wc * 64 + ct * 16 + lrow;
      const float bias = sBias[biasOff + col];
      #pragma unroll
      for (int r = 0; r < 4; ++r) {
        const int orow = wr * 32 + rt * 16 + lk * 4 + r;
        float v = acc[rt][ct][r] + bias;
        v = fmaxf(v, 0.f);
        *(u16*)((char*)sIn + swz256(orow, col * 2)) = f2bf(v);
        acc[rt][ct][r] = 0.f;
      }
    }
  }
}

static __device__ __forceinline__ void store_h3(float* sH, const float* sBias,
                                                int wr, int wc, int lrow, int lk,
                                                f32x4 acc[2][4]) {
  #pragma unroll
  for (int rt = 0; rt < 2; ++rt) {
    #pragma unroll
    for (int ct = 0; ct < 4; ++ct) {
      const int col = wc * 64 + ct * 16 + lrow;
      const float bias = sBias[256 + col];
      #pragma unroll
      for (int r = 0; r < 4; ++r) {
        const int orow = wr * 32 + rt * 16 + lk * 4 + r;
        sH[orow * 132 + col] = acc[rt][ct][r] + bias;
      }
    }
  }
}

// ---------------- edge conv: msg = LN(MLP([x_dst[i], x_src[j], ea])); ea += msg; msg stored per edge
__global__ __launch_bounds__(256, 2) void edge_conv_kernel(
    const u16* __restrict__ xsrc, const u16* __restrict__ xdst,
    const int* __restrict__ ei, const int E,
    const float* __restrict__ ea_f32, u16* __restrict__ ea_bf,
    const u16* __restrict__ W0T, const u16* __restrict__ W1T, const u16* __restrict__ W2T,
    const float* __restrict__ b0, const float* __restrict__ b1, const float* __restrict__ b2,
    const float* __restrict__ gg, const float* __restrict__ btp,
    u16* __restrict__ msg_out)
{
  __shared__ u16 sIn[64 * 128];
  __shared__ __align__(16) char sWHraw[64 * 132 * 4];  // sW (32KB bf16) and sH (f32, pad 132) union
  __shared__ float sBias[5 * 128];
  __shared__ int sIdx[128];
  u16* sW = (u16*)sWHraw;
  float* sH = (float*)sWHraw;

  const int tid = threadIdx.x;
  const int wave = tid >> 6, lane = tid & 63;
  const int lrow = lane & 15, lk = lane >> 4;
  const int wr = wave >> 1, wc = wave & 1;
  const int e0 = blockIdx.x * 64;
  const int row = tid >> 2, seg = tid & 3;

  if (tid < 128) {
    sBias[tid] = b0[tid];
    sBias[128 + tid] = b1[tid];
    sBias[256 + tid] = b2[tid];
    sBias[384 + tid] = gg[tid];
    sBias[512 + tid] = btp[tid];
  }
  if (tid < 64) {
    int e = e0 + tid; if (e >= E) e = E - 1;
    sIdx[tid] = ei[e];          // src
    sIdx[64 + tid] = ei[E + e]; // dst
  }
  __syncthreads();

  const int eRow = (e0 + row < E) ? (e0 + row) : (E - 1);
  const f32x4 zero = {0.f, 0.f, 0.f, 0.f};
  f32x4 acc[2][4];
  #pragma unroll
  for (int i = 0; i < 2; ++i)
    #pragma unroll
    for (int j = 0; j < 4; ++j) acc[i][j] = zero;

  // ----- layer 1: three K=128 parts (x_dst, x_src, ea) -----
  #pragma unroll
  for (int p = 0; p < 3; ++p) {
    if (p < 2) {
      const u16* xb = (p == 0) ? xdst : xsrc;
      const int idx = (p == 0) ? sIdx[64 + row] : sIdx[row];
      const u16* srow = xb + (size_t)idx * DD;
      #pragma unroll
      for (int j = 0; j < 4; ++j) {
        short8 v = *(const short8*)(srow + seg * 32 + j * 8);
        *(short8*)((char*)sIn + swz256(row, seg * 64 + j * 16)) = v;
      }
    } else if (ea_f32) {
      const float* er = ea_f32 + (size_t)eRow * DD;
      #pragma unroll
      for (int j = 0; j < 4; ++j) {
        const int c0 = seg * 32 + j * 8;
        f32x4 f0 = *(const f32x4*)(er + c0);
        f32x4 f1 = *(const f32x4*)(er + c0 + 4);
        short8 v;
        #pragma unroll
        for (int q = 0; q < 4; ++q) { v[q] = (short)f2bf(f0[q]); v[4 + q] = (short)f2bf(f1[q]); }
        *(short8*)((char*)sIn + swz256(row, seg * 64 + j * 16)) = v;
      }
    } else {
      const u16* er = ea_bf + (size_t)eRow * DD;
      #pragma unroll
      for (int j = 0; j < 4; ++j) {
        short8 v = *(const short8*)(er + seg * 32 + j * 8);
        *(short8*)((char*)sIn + swz256(row, seg * 64 + j * 16)) = v;
      }
    }
    stage_w(sW, W0T, 384, p * 128, tid);
    __syncthreads();
    mfma_128k(sIn, sW, wr, wc, lrow, lk, acc);
    __syncthreads();
  }

  transition_relu(sIn, sBias, 0, wr, wc, lrow, lk, acc);
  stage_w(sW, W1T, 128, 0, tid);
  __syncthreads();
  mfma_128k(sIn, sW, wr, wc, lrow, lk, acc);
  __syncthreads();

  transition_relu(sIn, sBias, 128, wr, wc, lrow, lk, acc);
  stage_w(sW, W2T, 128, 0, tid);
  __syncthreads();
  mfma_128k(sIn, sW, wr, wc, lrow, lk, acc);
  __syncthreads();                 // all L3 B-reads done before sH overwrites sW

  store_h3(sH, sBias, wr, wc, lrow, lk, acc);
  __syncthreads();

  // ----- epilogue: LN per edge row, residual into ea (bf16), msg stored (bf16) -----
  {
    const float* hrow = sH + row * 132 + seg * 32;
    f32x4 vv[8];
    float s1 = 0.f, s2 = 0.f;
    #pragma unroll
    for (int j = 0; j < 8; ++j) {
      vv[j] = *(const f32x4*)(hrow + j * 4);
      #pragma unroll
      for (int q = 0; q < 4; ++q) { s1 += vv[j][q]; s2 += vv[j][q] * vv[j][q]; }
    }
    s1 += __shfl_xor(s1, 1); s1 += __shfl_xor(s1, 2);
    s2 += __shfl_xor(s2, 1); s2 += __shfl_xor(s2, 2);
    const float m = s1 * (1.f / 128.f);
    const float var = s2 * (1.f / 128.f) - m * m;
    const float rstd = rsqrtf(var + 1e-5f);
    const int e = e0 + row;
    if (e < E) {
      u16* eaRow = ea_bf + (size_t)e * DD + seg * 32;
      u16* msgRow = msg_out + (size_t)e * DD + seg * 32;
      float eold[32];
      if (ea_f32) {
        const float* er = ea_f32 + (size_t)e * DD + seg * 32;
        #pragma unroll
        for (int j = 0; j < 8; ++j) {
          f32x4 t = *(const f32x4*)(er + j * 4);
          #pragma unroll
          for (int q = 0; q < 4; ++q) eold[j * 4 + q] = t[q];
        }
      } else {
        #pragma unroll
        for (int j4 = 0; j4 < 4; ++j4) {
          short8 t = *(const short8*)(eaRow + j4 * 8);
          #pragma unroll
          for (int q = 0; q < 8; ++q) eold[j4 * 8 + q] = bf2f((u16)t[q]);
        }
      }
      #pragma unroll
      for (int j4 = 0; j4 < 4; ++j4) {
        short8 en, ms;
        #pragma unroll
        for (int q = 0; q < 8; ++q) {
          const int cl = j4 * 8 + q;
          const int c = seg * 32 + cl;
          const float msg = (vv[cl >> 2][cl & 3] - m) * rstd * sBias[384 + c] + sBias[512 + c];
          en[q] = (short)f2bf(eold[cl] + msg);
          ms[q] = (short)f2bf(msg);
        }
        *(short8*)(eaRow + j4 * 8) = en;
        *(short8*)(msgRow + j4 * 8) = ms;
      }
    }
  }
}

// ---------------- CSR build: histogram -> scan -> scatter ----------------
__global__ void hist_kernel(const int* __restrict__ ei, int E, int* __restrict__ deg) {
  int i = blockIdx.x * blockDim.x + threadIdx.x;
  if (i < E) atomicAdd(&deg[ei[E + i]], 1);  // dst = ei[1][i]
}

__global__ __launch_bounds__(1024) void scan_kernel(const int* __restrict__ deg,
                                                    int* __restrict__ start,
                                                    int* __restrict__ cursor, int N) {
  __shared__ int lds[1024];
  const int t = threadIdx.x;
  const int chunk = (N + 1023) >> 10;
  const int base = t * chunk;
  const int end = min(base + chunk, N);
  int s = 0;
  for (int i = base; i < end; ++i) s += deg[i];
  lds[t] = s;
  __syncthreads();
  for (int d = 1; d < 1024; d <<= 1) {
    int v = (t >= d) ? lds[t - d] : 0;
    __syncthreads();
    lds[t] += v;
    __syncthreads();
  }
  int off = lds[t] - s;  // exclusive prefix for this chunk
  for (int i = base; i < end; ++i) { start[i] = off; cursor[i] = off; off += deg[i]; }
  if (t == 1023) start[N] = lds[1023];
}

__global__ void scatter_kernel(const int* __restrict__ ei, int E,
                               int* __restrict__ cursor, int* __restrict__ perm) {
  int i = blockIdx.x * blockDim.x + threadIdx.x;
  if (i < E) { int p = atomicAdd(&cursor[ei[E + i]], 1); perm[p] = i; }
}

// ---------------- aggregate: agg[n] = sum of msg rows of incoming edges (CSR gather)
__global__ __launch_bounds__(256) void agg_gather_kernel(
    const u16* __restrict__ msg, const int* __restrict__ start,
    const int* __restrict__ perm, float* __restrict__ agg, int N)
{
  const int wave = threadIdx.x >> 6, lane = threadIdx.x & 63;
  const int n = blockIdx.x * 4 + wave;
  if (n >= N) return;
  const int i0 = start[n], i1 = start[n + 1];
  float a0 = 0.f, a1 = 0.f;
  for (int i = i0; i < i1; ++i) {
    const int e = perm[i];
    unsigned v = *(const unsigned*)(msg + (size_t)e * DD + lane * 2);
    a0 += bf2f((u16)(v & 0xFFFFu));
    a1 += bf2f((u16)(v >> 16));
  }
  float* ar = agg + (size_t)n * DD + lane * 2;
  ar[0] = a0;
  ar[1] = a1;
}

// ---------------- node conv: x += LN(MLP([x, aggr]))
__global__ __launch_bounds__(256, 2) void node_conv_kernel(
    u16* __restrict__ x_bf, const float* __restrict__ aggin,
    float* __restrict__ x_f32, const int N,
    const u16* __restrict__ W0T, const u16* __restrict__ W1T, const u16* __restrict__ W2T,
    const float* __restrict__ b0, const float* __restrict__ b1, const float* __restrict__ b2,
    const float* __restrict__ gg, const float* __restrict__ btp)
{
  __shared__ u16 sIn[64 * 128];
  __shared__ __align__(16) char sWHraw[64 * 132 * 4];
  __shared__ float sBias[5 * 128];
  u16* sW = (u16*)sWHraw;
  float* sH = (float*)sWHraw;

  const int tid = threadIdx.x;
  const int wave = tid >> 6, lane = tid & 63;
  const int lrow = lane & 15, lk = lane >> 4;
  const int wr = wave >> 1, wc = wave & 1;
  const int n0 = blockIdx.x * 64;
  const int row = tid >> 2, seg = tid & 3;
  const int nRow = (n0 + row < N) ? (n0 + row) : (N - 1);

  if (tid < 128) {
    sBias[tid] = b0[tid];
    sBias[128 + tid] = b1[tid];
    sBias[256 + tid] = b2[tid];
    sBias[384 + tid] = gg[tid];
    sBias[512 + tid] = btp[tid];
  }
  __syncthreads();

  const f32x4 zero = {0.f, 0.f, 0.f, 0.f};
  f32x4 acc[2][4];
  #pragma unroll
  for (int i = 0; i < 2; ++i)
    #pragma unroll
    for (int j = 0; j < 4; ++j) acc[i][j] = zero;

  // part 0: x
  {
    const u16* srow = x_bf + (size_t)nRow * DD;
    #pragma unroll
    for (int j = 0; j < 4; ++j) {
      short8 v = *(const short8*)(srow + seg * 32 + j * 8);
      *(short8*)((char*)sIn + swz256(row, seg * 64 + j * 16)) = v;
    }
    stage_w(sW, W0T, 256, 0, tid);
  }
  __syncthreads();
  mfma_128k(sIn, sW, wr, wc, lrow, lk, acc);
  __syncthreads();
  // part 1: aggr (f32 -> bf16)
  {
    const float* ar = aggin + (size_t)nRow * DD;
    #pragma unroll
    for (int j = 0; j < 4; ++j) {
      const int c0 = seg * 32 + j * 8;
      f32x4 f0 = *(const f32x4*)(ar + c0);
      f32x4 f1 = *(const f32x4*)(ar + c0 + 4);
      short8 v;
      #pragma unroll
      for (int q = 0; q < 4; ++q) { v[q] = (short)f2bf(f0[q]); v[4 + q] = (short)f2bf(f1[q]); }
      *(short8*)((char*)sIn + swz256(row, seg * 64 + j * 16)) = v;
    }
    stage_w(sW, W0T, 256, 128, tid);
  }
  __syncthreads();
  mfma_128k(sIn, sW, wr, wc, lrow, lk, acc);
  __syncthreads();

  transition_relu(sIn, sBias, 0, wr, wc, lrow, lk, acc);
  stage_w(sW, W1T, 128, 0, tid);
  __syncthreads();
  mfma_128k(sIn, sW, wr, wc, lrow, lk, acc);
  __syncthreads();

  transition_relu(sIn, sBias, 128, wr, wc, lrow, lk, acc);
  stage_w(sW, W2T, 128, 0, tid);
  __syncthreads();
  mfma_128k(sIn, sW, wr, wc, lrow, lk, acc);
  __syncthreads();

  store_h3(sH, sBias, wr, wc, lrow, lk, acc);
  __syncthreads();

  // epilogue: LN + residual, write f32 (d_out) and bf16 copy
  {
    const float* hrow = sH + row * 132 + seg * 32;
    f32x4 vv[8];
    float s1 = 0.f, s2 = 0.f;
    #pragma unroll
    for (int j = 0; j < 8; ++j) {
      vv[j] = *(const f32x4*)(hrow + j * 4);
      #pragma unroll
      for (int q = 0; q < 4; ++q) { s1 += vv[j][q]; s2 += vv[j][q] * vv[j][q]; }
    }
    s1 += __shfl_xor(s1, 1); s1 += __shfl_xor(s1, 2);
    s2 += __shfl_xor(s2, 1); s2 += __shfl_xor(s2, 2);
    const float m = s1 * (1.f / 128.f);
    const float var = s2 * (1.f / 128.f) - m * m;
    const float rstd = rsqrtf(var + 1e-5f);
    const int n = n0 + row;
    if (n < N) {
      float* xr = x_f32 + (size_t)n * DD + seg * 32;
      u16* xb = x_bf + (size_t)n * DD + seg * 32;
      #pragma unroll
      for (int j = 0; j < 8; ++j) {
        f32x4 xold = *(const f32x4*)(xr + j * 4);
        f32x4 nv;
        short4v pb;
        #pragma unroll
        for (int q = 0; q < 4; ++q) {
          const int c = seg * 32 + j * 4 + q;
          const float ln = (vv[j][q] - m) * rstd * sBias[384 + c] + sBias[512 + c];
          nv[q] = xold[q] + ln;
          pb[q] = (short)f2bf(nv[q]);
        }
        *(f32x4*)(xr + j * 4) = nv;
        *(short4v*)(xb + j * 4) = pb;
      }
    }
  }
}

// ---------------- prep: weights f32 [4][K][128] -> bf16 transposed [4][128][K]
__global__ void prep_w_kernel(const float* __restrict__ src, u16* __restrict__ dst, int K) {
  int i = blockIdx.x * blockDim.x + threadIdx.x;
  int total = 4 * K * 128;
  if (i < total) {
    int n = i & 127;
    int k = (i >> 7) % K;
    int sl = i / (K * 128);
    dst[((size_t)sl * 128 + n) * K + k] = f2bf(src[i]);
  }
}

// prep: x f32 -> d_out working copy + bf16 copies
__global__ void prep_x_kernel(const float* __restrict__ xm, const float* __restrict__ xo,
                              float* __restrict__ xf, u16* __restrict__ xmb, u16* __restrict__ xob) {
  int i = blockIdx.x * blockDim.x + threadIdx.x;
  const int tm = NMESH * DD;
  const int to = NOBJ * DD;
  if (i < tm) { float v = xm[i]; xf[i] = v; xmb[i] = f2bf(v); }
  else if (i < tm + to) { int j = i - tm; float v = xo[j]; xf[tm + j] = v; xob[j] = f2bf(v); }
}

extern "C" void kernel_launch(void* const* d_in, const int* in_sizes, int n_in,
                              void* d_out, int out_size, void* d_ws, size_t ws_size,
                              hipStream_t stream)
{
  const float* x_mesh = (const float*)d_in[0];
  const float* x_obj  = (const float*)d_in[1];
  const int*   ei_mm  = (const int*)d_in[2];
  const int*   ei_mo  = (const int*)d_in[3];
  const float* ea_mm  = (const float*)d_in[4];
  const float* ea_mo  = (const float*)d_in[5];
  const float* eW0 = (const float*)d_in[6];
  const float* eb0 = (const float*)d_in[7];
  const float* eW1 = (const float*)d_in[8];
  const float* eb1 = (const float*)d_in[9];
  const float* eW2 = (const float*)d_in[10];
  const float* eb2 = (const float*)d_in[11];
  const float* eg  = (const float*)d_in[12];
  const float* ebt = (const float*)d_in[13];
  const float* nW0 = (const float*)d_in[14];
  const float* nb0 = (const float*)d_in[15];
  const float* nW1 = (const float*)d_in[16];
  const float* nb1 = (const float*)d_in[17];
  const float* nW2 = (const float*)d_in[18];
  const float* nb2 = (const float*)d_in[19];
  const float* ng  = (const float*)d_in[20];
  const float* nbt = (const float*)d_in[21];

  u16* eamm_bf = (u16*)d_ws;
  u16* eamo_bf = eamm_bf + (size_t)EMMN * DD;
  u16* xm_bf   = eamo_bf + (size_t)EMON * DD;
  u16* xo_bf   = xm_bf + (size_t)NMESH * DD;
  float* agg_m = (float*)(xo_bf + (size_t)NOBJ * DD);
  float* agg_o = agg_m + (size_t)NMESH * DD;
  u16* eW0T = (u16*)(agg_o + (size_t)NOBJ * DD);
  u16* eW1T = eW0T + (size_t)4 * 128 * 384;
  u16* eW2T = eW1T + (size_t)4 * 128 * 128;
  u16* nW0T = eW2T + (size_t)4 * 128 * 128;
  u16* nW1T = nW0T + (size_t)4 * 128 * 256;
  u16* nW2T = nW1T + (size_t)4 * 128 * 128;
  u16* msg_mm = nW2T + (size_t)4 * 128 * 128;
  u16* msg_mo = msg_mm + (size_t)EMMN * DD;
  int* deg_m   = (int*)(msg_mo + (size_t)EMON * DD);
  int* start_m = deg_m + NMESH;
  int* cur_m   = start_m + NMESH + 1;
  int* perm_mm = cur_m + NMESH;
  int* deg_o   = perm_mm + EMMN;
  int* start_o = deg_o + NOBJ;
  int* cur_o   = start_o + NOBJ + 1;
  int* perm_mo = cur_o + NOBJ;

  float* xf_m = (float*)d_out;
  float* xf_o = xf_m + (size_t)NMESH * DD;

  prep_w_kernel<<<768, 256, 0, stream>>>(eW0, eW0T, 384);
  prep_w_kernel<<<256, 256, 0, stream>>>(eW1, eW1T, 128);
  prep_w_kernel<<<256, 256, 0, stream>>>(eW2, eW2T, 128);
  prep_w_kernel<<<512, 256, 0, stream>>>(nW0, nW0T, 256);
  prep_w_kernel<<<256, 256, 0, stream>>>(nW1, nW1T, 128);
  prep_w_kernel<<<256, 256, 0, stream>>>(nW2, nW2T, 128);
  prep_x_kernel<<<16000, 256, 0, stream>>>(x_mesh, x_obj, xf_m, xm_bf, xo_bf);

  // CSR build (indices are launch-invariant; built fresh each launch for determinism)
  hipMemsetAsync(deg_m, 0, NMESH * sizeof(int), stream);
  hipMemsetAsync(deg_o, 0, NOBJ * sizeof(int), stream);
  hist_kernel<<<(EMMN + 255) / 256, 256, 0, stream>>>(ei_mm, EMMN, deg_m);
  hist_kernel<<<(EMON + 255) / 256, 256, 0, stream>>>(ei_mo, EMON, deg_o);
  scan_kernel<<<1, 1024, 0, stream>>>(deg_m, start_m, cur_m, NMESH);
  scan_kernel<<<1, 1024, 0, stream>>>(deg_o, start_o, cur_o, NOBJ);
  scatter_kernel<<<(EMMN + 255) / 256, 256, 0, stream>>>(ei_mm, EMMN, cur_m, perm_mm);
  scatter_kernel<<<(EMON + 255) / 256, 256, 0, stream>>>(ei_mo, EMON, cur_o, perm_mo);

  for (int s = 0; s < 2; ++s) {
    {
      int sl = 0 * 2 + s;
      edge_conv_kernel<<<EMMN / 64, 256, 0, stream>>>(
          xm_bf, xm_bf, ei_mm, EMMN,
          (s == 0) ? ea_mm : (const float*)nullptr, eamm_bf,
          eW0T + (size_t)sl * 128 * 384, eW1T + (size_t)sl * 128 * 128, eW2T + (size_t)sl * 128 * 128,
          eb0 + sl * 128, eb1 + sl * 128, eb2 + sl * 128, eg + sl * 128, ebt + sl * 128,
          msg_mm);
    }
    {
      int sl = 1 * 2 + s;
      edge_conv_kernel<<<(EMON + 63) / 64, 256, 0, stream>>>(
          xm_bf, xo_bf, ei_mo, EMON,
          (s == 0) ? ea_mo : (const float*)nullptr, eamo_bf,
          eW0T + (size_t)sl * 128 * 384, eW1T + (size_t)sl * 128 * 128, eW2T + (size_t)sl * 128 * 128,
          eb0 + sl * 128, eb1 + sl * 128, eb2 + sl * 128, eg + sl * 128, ebt + sl * 128,
          msg_mo);
    }
    agg_gather_kernel<<<(NMESH + 3) / 4, 256, 0, stream>>>(msg_mm, start_m, perm_mm, agg_m, NMESH);
    agg_gather_kernel<<<(NOBJ + 3) / 4, 256, 0, stream>>>(msg_mo, start_o, perm_mo, agg_o, NOBJ);
    {
      int sl = 0 * 2 + s;
      node_conv_kernel<<<(NMESH + 63) / 64, 256, 0, stream>>>(
          xm_bf, agg_m, xf_m, NMESH,
          nW0T + (size_t)sl * 128 * 256, nW1T + (size_t)sl * 128 * 128, nW2T + (size_t)sl * 128 * 128,
          nb0 + sl * 128, nb1 + sl * 128, nb2 + sl * 128, ng + sl * 128, nbt + sl * 128);
    }
    {
      int sl = 1 * 2 + s;
      node_conv_kernel<<<(NOBJ + 63) / 64, 256, 0, stream>>>(
          xo_bf, agg_o, xf_o, NOBJ,
          nW0T + (size_t)sl * 128 * 256, nW1T + (size_t)sl * 128 * 128, nW2T + (size_t)sl * 128 * 128,
          nb0 + sl * 128, nb1 + sl * 128, nb2 + sl * 128, ng + sl * 128, nbt + sl * 128);
    }
  }
}